// Round 5
// baseline (319.147 us; speedup 1.0000x reference)
//
#include <hip/hip_runtime.h>
#include <hip/hip_bf16.h>
#include <stdint.h>

#define CC 256
#define CQD 32
#define NND 4096

typedef __bf16 bf16x8 __attribute__((ext_vector_type(8)));
typedef float f32x4 __attribute__((ext_vector_type(4)));

__device__ __forceinline__ bf16x8 ld_bf16x8(const __bf16* p) {
    return *reinterpret_cast<const bf16x8*>(p);
}

// ---------------- weight conversion ----------------
__global__ __launch_bounds__(256) void prep_weights(
    const float* __restrict__ wq, const float* __restrict__ wk,
    const float* __restrict__ wv, __bf16* __restrict__ wqkb,
    __bf16* __restrict__ wvb) {
    int i = blockIdx.x * 256 + threadIdx.x;
    if (i < 32 * 256) {
        wqkb[i] = (__bf16)wq[i];
    } else if (i < 64 * 256) {
        wqkb[i] = (__bf16)wk[i - 32 * 256];
    } else {
        int j = i - 64 * 256;
        if (j < 256 * 256) wvb[j] = (__bf16)wv[j];
    }
}

// ---------------- fused transpose + q/k/v projection ----------------
// Reads x [b][C][N] f32 directly; transposes a 64n x 256c tile into an
// XOR-swizzled bf16 LDS tile (b128-floor conflict-free for both the
// transposed writes and the B-fragment reads); then MFMA-projects
// q[b][N][32], k[b][N][32], v[b][C][N]. Grid linear, b = blk&7 (XCD swizzle).
__global__ __launch_bounds__(256, 2) void proj_qkv(
    const float* __restrict__ x, const __bf16* __restrict__ wqkb,
    const __bf16* __restrict__ wvb, const float* __restrict__ bq,
    const float* __restrict__ bk, const float* __restrict__ bv,
    __bf16* __restrict__ qb, __bf16* __restrict__ kb,
    __bf16* __restrict__ vb) {
    __shared__ __align__(16) __bf16 xt[64 * 256];  // 32 KB, xor-swizzled rows

    const int blk = blockIdx.x;
    const int b = blk & 7;
    const int n0 = (blk >> 3) * 64;
    const int tid = threadIdx.x;

    // phase 1: x[c][n0+tx] -> xt[n][c] (bf16, chunk-xor swizzle)
    {
        const int tx = tid & 63;  // n-local
        const int ty = tid >> 6;  // 0..3
        const float* xcol = x + (size_t)b * CC * NND + n0 + tx;
#pragma unroll
        for (int it = 0; it < 8; it++) {
            int c8 = it * 4 + ty;  // chunk 0..31
            int c = c8 * 8;
            union { bf16x8 v; __bf16 h[8]; } pk;
#pragma unroll
            for (int u = 0; u < 8; u++)
                pk.h[u] = (__bf16)xcol[(size_t)(c + u) * NND];
            *reinterpret_cast<bf16x8*>(&xt[tx * 256 + ((c8 ^ (tx & 7)) * 8)]) = pk.v;
        }
    }
    __syncthreads();

    // phase 2: GEMM from LDS tile
    const int lane = tid & 63;
    const int w = tid >> 6;
    const int l15 = lane & 15;
    const int quad = lane >> 4;
    const int row = w * 16 + l15;  // n-local
    const int n = n0 + row;
    const f32x4 fzero = {0.f, 0.f, 0.f, 0.f};
    f32x4 aqk[4];
    f32x4 av[16];
#pragma unroll
    for (int i = 0; i < 4; i++) aqk[i] = fzero;
#pragma unroll
    for (int i = 0; i < 16; i++) av[i] = fzero;
#pragma unroll
    for (int k0 = 0; k0 < CC; k0 += 32) {
        int g = (k0 >> 3) + quad;
        bf16x8 bf = ld_bf16x8(&xt[row * 256 + ((g ^ (row & 7)) * 8)]);
#pragma unroll
        for (int mt = 0; mt < 4; mt++) {
            bf16x8 af = ld_bf16x8(wqkb + (size_t)(mt * 16 + l15) * CC + k0 + quad * 8);
            aqk[mt] = __builtin_amdgcn_mfma_f32_16x16x32_bf16(af, bf, aqk[mt], 0, 0, 0);
        }
#pragma unroll
        for (int mt = 0; mt < 16; mt++) {
            bf16x8 af = ld_bf16x8(wvb + (size_t)(mt * 16 + l15) * CC + k0 + quad * 8);
            av[mt] = __builtin_amdgcn_mfma_f32_16x16x32_bf16(af, bf, av[mt], 0, 0, 0);
        }
    }
#pragma unroll
    for (int mt = 0; mt < 4; mt++) {
        const int ob = (mt & 1) * 16 + quad * 4;
        const float* bias = (mt < 2) ? bq : bk;
        __bf16* dst = ((mt < 2) ? qb : kb) + ((size_t)b * NND + n) * CQD + ob;
        union { ushort4 u; __bf16 h[4]; } pk;
#pragma unroll
        for (int r = 0; r < 4; r++) pk.h[r] = (__bf16)(aqk[mt][r] + bias[ob + r]);
        *reinterpret_cast<ushort4*>(dst) = pk.u;
    }
#pragma unroll
    for (int mt = 0; mt < 16; mt++) {
#pragma unroll
        for (int r = 0; r < 4; r++) {
            int c = mt * 16 + quad * 4 + r;
            vb[((size_t)b * CC + c) * NND + n] = (__bf16)(av[mt][r] + bv[c]);
        }
    }
}

// ---------------- fused flash attention + epilogue ----------------
// TI=128 i/block, 512 threads (8 waves, 2/SIMD), 1 block/CU, grid 256 linear
// with b = blk&7 (XCD swizzle: per-batch V/K/Q working set ~2.5 MB fits the
// 4 MB per-XCD L2). S^T formulation: wave w owns i-tile w (16 rows), per-lane
// softmax. PV: wave = c-slice (w>>1) x i-half (w&1), V direct from global
// (L2-hit) prefetched one j-step ahead into regs. Pt/aL double-buffered ->
// ONE barrier per j-step.
__global__ __launch_bounds__(512, 2) void attention(
    const __bf16* __restrict__ qb, const __bf16* __restrict__ kb,
    const __bf16* __restrict__ vb, const float* __restrict__ gamma,
    const float* __restrict__ x, float* __restrict__ out) {
    __shared__ __align__(16) __bf16 Pt[2][128 * 72];  // 2 x 18432 B
    __shared__ float aL[2][128];
    __shared__ float lL[128];

    const int blk = blockIdx.x;
    const int b = blk & 7;
    const int i0 = (blk >> 3) * 128;
    const int tid = threadIdx.x;
    const int w = tid >> 6;  // 0..7
    const int lane = tid & 63;
    const int l15 = lane & 15;
    const int quad = lane >> 4;
    const int cs = w >> 1;  // c-slice 0..3
    const int ih = w & 1;   // i-half 0..1
    const f32x4 fzero = {0.f, 0.f, 0.f, 0.f};

    // Q fragment (B-operand): i = i0 + w*16 + l15
    const bf16x8 qf = ld_bf16x8(qb + ((size_t)b * NND + i0 + w * 16 + l15) * CQD + quad * 8);

    const __bf16* kbase = kb + (size_t)b * NND * CQD + l15 * CQD + quad * 8;
    const __bf16* vbase = vb + ((size_t)(b * CC + cs * 64 + l15)) * NND + quad * 8;

    f32x4 acc[4][4];  // [ct][it]: c = cs*64+ct*16+quad*4+r, i = i0+ih*64+it*16+l15
#pragma unroll
    for (int ct = 0; ct < 4; ct++)
#pragma unroll
        for (int it = 0; it < 4; it++) acc[ct][it] = fzero;
    float m_i = -1e30f;
    float l_i = 0.f;

    // ---- prologue: K(0), V(0), S(0) -> Pt[0], aL[0] ----
    bf16x8 kf[4];
#pragma unroll
    for (int jt = 0; jt < 4; jt++)
        kf[jt] = ld_bf16x8(kbase + (size_t)jt * 16 * CQD);
    bf16x8 vf[8];
#pragma unroll
    for (int ks = 0; ks < 2; ks++)
#pragma unroll
        for (int ct = 0; ct < 4; ct++)
            vf[ks * 4 + ct] = ld_bf16x8(vbase + (size_t)ct * 16 * NND + ks * 32);
    {
        f32x4 sT[4];
#pragma unroll
        for (int jt = 0; jt < 4; jt++)
            sT[jt] = __builtin_amdgcn_mfma_f32_16x16x32_bf16(kf[jt], qf, fzero, 0, 0, 0);
#pragma unroll
        for (int jt = 0; jt < 4; jt++)
            kf[jt] = ld_bf16x8(kbase + (size_t)(64 + jt * 16) * CQD);
        float mx = -1e30f;
#pragma unroll
        for (int jt = 0; jt < 4; jt++)
#pragma unroll
            for (int r = 0; r < 4; r++) mx = fmaxf(mx, sT[jt][r]);
        mx = fmaxf(mx, __shfl_xor(mx, 16));
        mx = fmaxf(mx, __shfl_xor(mx, 32));
        m_i = mx;
        float ps = 0.f;
#pragma unroll
        for (int jt = 0; jt < 4; jt++) {
            union { ushort4 u4; __bf16 h[4]; } pk;
#pragma unroll
            for (int r = 0; r < 4; r++) {
                float p = __expf(sT[jt][r] - mx);
                ps += p;
                pk.h[r] = (__bf16)p;
            }
            *reinterpret_cast<ushort4*>(&Pt[0][(w * 16 + l15) * 72 + jt * 16 + quad * 4]) = pk.u4;
        }
        ps += __shfl_xor(ps, 16);
        ps += __shfl_xor(ps, 32);
        l_i = ps;
        if (quad == 0) aL[0][w * 16 + l15] = 1.0f;
    }
    __syncthreads();

    // ---- main loop: one barrier per step ----
    for (int j0 = 0; j0 < NND; j0 += 64) {
        const int pb = (j0 >> 6) & 1;
        // A-phase: S/softmax for step j0+64 -> Pt[pb^1], aL[pb^1]
        if (j0 + 64 < NND) {
            f32x4 sT[4];
#pragma unroll
            for (int jt = 0; jt < 4; jt++)
                sT[jt] = __builtin_amdgcn_mfma_f32_16x16x32_bf16(kf[jt], qf, fzero, 0, 0, 0);
            if (j0 + 128 < NND) {
#pragma unroll
                for (int jt = 0; jt < 4; jt++)
                    kf[jt] = ld_bf16x8(kbase + (size_t)(j0 + 128 + jt * 16) * CQD);
            }
            float mx = -1e30f;
#pragma unroll
            for (int jt = 0; jt < 4; jt++)
#pragma unroll
                for (int r = 0; r < 4; r++) mx = fmaxf(mx, sT[jt][r]);
            mx = fmaxf(mx, __shfl_xor(mx, 16));
            mx = fmaxf(mx, __shfl_xor(mx, 32));
            float mnew = fmaxf(m_i, mx);
            float alpha = __expf(m_i - mnew);
            m_i = mnew;
            float ps = 0.f;
#pragma unroll
            for (int jt = 0; jt < 4; jt++) {
                union { ushort4 u4; __bf16 h[4]; } pk;
#pragma unroll
                for (int r = 0; r < 4; r++) {
                    float p = __expf(sT[jt][r] - mnew);
                    ps += p;
                    pk.h[r] = (__bf16)p;
                }
                *reinterpret_cast<ushort4*>(
                    &Pt[pb ^ 1][(w * 16 + l15) * 72 + jt * 16 + quad * 4]) = pk.u4;
            }
            ps += __shfl_xor(ps, 16);
            ps += __shfl_xor(ps, 32);
            l_i = l_i * alpha + ps;
            if (quad == 0) aL[pb ^ 1][w * 16 + l15] = alpha;
        }
        // V prefetch for step j0+64
        bf16x8 vnxt[8];
        if (j0 + 64 < NND) {
#pragma unroll
            for (int ks = 0; ks < 2; ks++)
#pragma unroll
                for (int ct = 0; ct < 4; ct++)
                    vnxt[ks * 4 + ct] =
                        ld_bf16x8(vbase + (size_t)ct * 16 * NND + j0 + 64 + ks * 32);
        }
        // B-phase: PV(j0) with vf regs + Pt[pb]
        float avs[4];
#pragma unroll
        for (int it = 0; it < 4; it++) avs[it] = aL[pb][ih * 64 + it * 16 + l15];
#pragma unroll
        for (int ct = 0; ct < 4; ct++)
#pragma unroll
            for (int it = 0; it < 4; it++) acc[ct][it] *= avs[it];
#pragma unroll
        for (int ks = 0; ks < 2; ks++) {
#pragma unroll
            for (int it = 0; it < 4; it++) {
                bf16x8 pf = ld_bf16x8(
                    &Pt[pb][(ih * 64 + it * 16 + l15) * 72 + ks * 32 + quad * 8]);
#pragma unroll
                for (int ct = 0; ct < 4; ct++)
                    acc[ct][it] = __builtin_amdgcn_mfma_f32_16x16x32_bf16(
                        vf[ks * 4 + ct], pf, acc[ct][it], 0, 0, 0);
            }
        }
        if (j0 + 64 < NND) {
#pragma unroll
            for (int t = 0; t < 8; t++) vf[t] = vnxt[t];
        }
        __syncthreads();
    }

    // epilogue: out = gamma * O / l + x
    if (quad == 0) lL[w * 16 + l15] = l_i;
    __syncthreads();
    float linv[4];
#pragma unroll
    for (int it = 0; it < 4; it++) linv[it] = 1.0f / lL[ih * 64 + it * 16 + l15];
    float g = gamma[0];
#pragma unroll
    for (int ct = 0; ct < 4; ct++) {
#pragma unroll
        for (int it = 0; it < 4; it++) {
#pragma unroll
            for (int r = 0; r < 4; r++) {
                int c = cs * 64 + ct * 16 + quad * 4 + r;
                int i = i0 + ih * 64 + it * 16 + l15;
                size_t off = ((size_t)b * CC + c) * NND + i;
                out[off] = g * (acc[ct][it][r] * linv[it]) + x[off];
            }
        }
    }
}

extern "C" void kernel_launch(void* const* d_in, const int* in_sizes, int n_in,
                              void* d_out, int out_size, void* d_ws, size_t ws_size,
                              hipStream_t stream) {
    const float* x = (const float*)d_in[0];
    const float* wq = (const float*)d_in[1];
    const float* bq = (const float*)d_in[2];
    const float* wk = (const float*)d_in[3];
    const float* bk = (const float*)d_in[4];
    const float* wv = (const float*)d_in[5];
    const float* bv = (const float*)d_in[6];
    const float* gamma = (const float*)d_in[7];
    float* out = (float*)d_out;

    char* ws = (char*)d_ws;
    __bf16* qb = (__bf16*)ws;                       // 8*4096*32*2  = 2097152
    __bf16* kb = (__bf16*)(ws + 2097152);           // 2097152
    __bf16* vb = (__bf16*)(ws + 2 * 2097152);       // 8*256*4096*2 = 16777216
    __bf16* wqkb = (__bf16*)(ws + 2 * 2097152 + 16777216);           // 32768
    __bf16* wvb = (__bf16*)(ws + 2 * 2097152 + 16777216 + 32768);    // 131072

    prep_weights<<<320, 256, 0, stream>>>(wq, wk, wv, wqkb, wvb);
    proj_qkv<<<512, 256, 0, stream>>>(x, wqkb, wvb, bq, bk, bv, qb, kb, vb);
    attention<<<256, 512, 0, stream>>>(qb, kb, vb, gamma, x, out);
}

// Round 6
// 242.344 us; speedup vs baseline: 1.3169x; 1.3169x over previous
//
#include <hip/hip_runtime.h>
#include <hip/hip_bf16.h>
#include <stdint.h>

#define CC 256
#define CQD 32
#define NND 4096

typedef __bf16 bf16x8 __attribute__((ext_vector_type(8)));
typedef float f32x4 __attribute__((ext_vector_type(4)));

__device__ __forceinline__ bf16x8 ld_bf16x8(const __bf16* p) {
    return *reinterpret_cast<const bf16x8*>(p);
}

// ---------------- weight conversion ----------------
__global__ __launch_bounds__(256) void prep_weights(
    const float* __restrict__ wq, const float* __restrict__ wk,
    const float* __restrict__ wv, __bf16* __restrict__ wqkb,
    __bf16* __restrict__ wvb) {
    int i = blockIdx.x * 256 + threadIdx.x;
    if (i < 32 * 256) {
        wqkb[i] = (__bf16)wq[i];
    } else if (i < 64 * 256) {
        wqkb[i] = (__bf16)wk[i - 32 * 256];
    } else {
        int j = i - 64 * 256;
        if (j < 256 * 256) wvb[j] = (__bf16)wv[j];
    }
}

// ---------------- fused transpose + q/k/v projection ----------------
__global__ __launch_bounds__(256, 2) void proj_qkv(
    const float* __restrict__ x, const __bf16* __restrict__ wqkb,
    const __bf16* __restrict__ wvb, const float* __restrict__ bq,
    const float* __restrict__ bk, const float* __restrict__ bv,
    __bf16* __restrict__ qb, __bf16* __restrict__ kb,
    __bf16* __restrict__ vb) {
    __shared__ __align__(16) __bf16 xt[64 * 256];  // 32 KB, xor-swizzled rows

    const int blk = blockIdx.x;
    const int b = blk & 7;
    const int n0 = (blk >> 3) * 64;
    const int tid = threadIdx.x;

    // phase 1: x[c][n0+tx] -> xt[n][c] (bf16, chunk-xor swizzle)
    {
        const int tx = tid & 63;  // n-local
        const int ty = tid >> 6;  // 0..3
        const float* xcol = x + (size_t)b * CC * NND + n0 + tx;
#pragma unroll
        for (int it = 0; it < 8; it++) {
            int c8 = it * 4 + ty;  // chunk 0..31
            int c = c8 * 8;
            union { bf16x8 v; __bf16 h[8]; } pk;
#pragma unroll
            for (int u = 0; u < 8; u++)
                pk.h[u] = (__bf16)xcol[(size_t)(c + u) * NND];
            *reinterpret_cast<bf16x8*>(&xt[tx * 256 + ((c8 ^ (tx & 7)) * 8)]) = pk.v;
        }
    }
    __syncthreads();

    // phase 2: GEMM from LDS tile
    const int lane = tid & 63;
    const int w = tid >> 6;
    const int l15 = lane & 15;
    const int quad = lane >> 4;
    const int row = w * 16 + l15;  // n-local
    const int n = n0 + row;
    const f32x4 fzero = {0.f, 0.f, 0.f, 0.f};
    f32x4 aqk[4];
    f32x4 av[16];
#pragma unroll
    for (int i = 0; i < 4; i++) aqk[i] = fzero;
#pragma unroll
    for (int i = 0; i < 16; i++) av[i] = fzero;
#pragma unroll
    for (int k0 = 0; k0 < CC; k0 += 32) {
        int g = (k0 >> 3) + quad;
        bf16x8 bf = ld_bf16x8(&xt[row * 256 + ((g ^ (row & 7)) * 8)]);
#pragma unroll
        for (int mt = 0; mt < 4; mt++) {
            bf16x8 af = ld_bf16x8(wqkb + (size_t)(mt * 16 + l15) * CC + k0 + quad * 8);
            aqk[mt] = __builtin_amdgcn_mfma_f32_16x16x32_bf16(af, bf, aqk[mt], 0, 0, 0);
        }
#pragma unroll
        for (int mt = 0; mt < 16; mt++) {
            bf16x8 af = ld_bf16x8(wvb + (size_t)(mt * 16 + l15) * CC + k0 + quad * 8);
            av[mt] = __builtin_amdgcn_mfma_f32_16x16x32_bf16(af, bf, av[mt], 0, 0, 0);
        }
    }
#pragma unroll
    for (int mt = 0; mt < 4; mt++) {
        const int ob = (mt & 1) * 16 + quad * 4;
        const float* bias = (mt < 2) ? bq : bk;
        __bf16* dst = ((mt < 2) ? qb : kb) + ((size_t)b * NND + n) * CQD + ob;
        union { ushort4 u; __bf16 h[4]; } pk;
#pragma unroll
        for (int r = 0; r < 4; r++) pk.h[r] = (__bf16)(aqk[mt][r] + bias[ob + r]);
        *reinterpret_cast<ushort4*>(dst) = pk.u;
    }
#pragma unroll
    for (int mt = 0; mt < 16; mt++) {
#pragma unroll
        for (int r = 0; r < 4; r++) {
            int c = mt * 16 + quad * 4 + r;
            vb[((size_t)b * CC + c) * NND + n] = (__bf16)(av[mt][r] + bv[c]);
        }
    }
}

// ---------------- fused flash attention + epilogue ----------------
// R3 structure + XCD swizzle. TI=64 i/block, 4 waves, 2 blocks/CU (grid 512
// linear, b = blk&7 so each XCD's 64 blocks share one batch: V/K/Q working
// set ~2.5 MB fits the 4 MB per-XCD L2 -> V re-reads come from L2, not L3).
// S^T formulation (A=K, B=Q): per-lane softmax rows. PV c-split: wave w owns
// c in [w*64, w*64+64). V staged via global_load_lds width=16 into
// XOR-swizzled LDS; K direct from global, prefetched 1 step ahead.
// 2 independent blocks/CU interleave softmax-VALU and PV-LDS/MFMA phases.
__global__ __launch_bounds__(256, 2) void attention(
    const __bf16* __restrict__ qb, const __bf16* __restrict__ kb,
    const __bf16* __restrict__ vb, const float* __restrict__ gamma,
    const float* __restrict__ x, float* __restrict__ out) {
    __shared__ __align__(16) __bf16 Vt[CC * 64];  // 32768 B, swizzled rows
    __shared__ __align__(16) __bf16 Pt[64 * 72];  // 9216 B, [i][j] stride 72
    __shared__ float aL[64];
    __shared__ float lL[64];

    const int blk = blockIdx.x;
    const int b = blk & 7;
    const int i0 = (blk >> 3) * 64;
    const int tid = threadIdx.x;
    const int w = tid >> 6;
    const int lane = tid & 63;
    const int l15 = lane & 15;
    const int quad = lane >> 4;
    const f32x4 fzero = {0.f, 0.f, 0.f, 0.f};

    // Q fragment (B-operand): n=i = i0 + w*16 + l15, k(c) = quad*8..
    bf16x8 qf = ld_bf16x8(qb + ((size_t)b * NND + i0 + w * 16 + l15) * CQD + quad * 8);

    // K fragments (A-operand) for j0 = 0: m=j = jt*16 + l15
    bf16x8 kf[4];
#pragma unroll
    for (int jt = 0; jt < 4; jt++)
        kf[jt] = ld_bf16x8(kb + ((size_t)b * NND + jt * 16 + l15) * CQD + quad * 8);

    // global_load_lds source: lane -> row w*64 + (lane>>3), chunk swizzled
    const int vrow = lane >> 3;
    const int vswz = ((lane & 7) ^ vrow) * 8;
    const __bf16* vsrc = vb + ((size_t)(b * CC + w * 64 + vrow)) * NND + vswz;
    __bf16* vdstb = &Vt[(w * 64) * 64];  // wave-uniform base; +lane*16B by HW

    f32x4 acc[4][4];  // [ct][it]: c = w*64+ct*16+quad*4+r, i = it*16+l15
#pragma unroll
    for (int ct = 0; ct < 4; ct++)
#pragma unroll
        for (int it = 0; it < 4; it++) acc[ct][it] = fzero;
    float m_i = -1e30f;
    float l_i = 0.f;
    const int swz = (l15 & 7) * 8;

    for (int j0 = 0; j0 < NND; j0 += 64) {
        __syncthreads();  // barrier 1: prev PV done -> safe to overwrite Vt/Pt
        // stage V(j0): 8 x global_load_lds width=16 per wave (own c-slice)
#pragma unroll
        for (int t = 0; t < 8; t++) {
            __builtin_amdgcn_global_load_lds(
                (const __attribute__((address_space(1))) void*)(vsrc + (size_t)t * 8 * NND + j0),
                (__attribute__((address_space(3))) void*)(vdstb + t * 8 * 64), 16, 0, 0);
        }
        // S^T = K Q^T : col = i (l15), row = j (jt*16 + quad*4 + r)
        f32x4 sT[4];
#pragma unroll
        for (int jt = 0; jt < 4; jt++)
            sT[jt] = __builtin_amdgcn_mfma_f32_16x16x32_bf16(kf[jt], qf, fzero, 0, 0, 0);
        // prefetch K(j0+64) into regs (consumed next iter)
        if (j0 + 64 < NND) {
#pragma unroll
            for (int jt = 0; jt < 4; jt++)
                kf[jt] = ld_bf16x8(kb + ((size_t)b * NND + j0 + 64 + jt * 16 + l15) * CQD + quad * 8);
        }
        // online softmax (per-lane row i = i0 + w*16 + l15) + P pack/write
        {
            float mx = -1e30f;
#pragma unroll
            for (int jt = 0; jt < 4; jt++)
#pragma unroll
                for (int r = 0; r < 4; r++) mx = fmaxf(mx, sT[jt][r]);
            mx = fmaxf(mx, __shfl_xor(mx, 16));
            mx = fmaxf(mx, __shfl_xor(mx, 32));
            float mnew = fmaxf(m_i, mx);
            float alpha = __expf(m_i - mnew);
            m_i = mnew;
            float ps = 0.f;
#pragma unroll
            for (int jt = 0; jt < 4; jt++) {
                union { ushort4 u4; __bf16 h[4]; } pk;
#pragma unroll
                for (int r = 0; r < 4; r++) {
                    float p = __expf(sT[jt][r] - mnew);
                    ps += p;
                    pk.h[r] = (__bf16)p;
                }
                *reinterpret_cast<ushort4*>(
                    &Pt[(w * 16 + l15) * 72 + jt * 16 + quad * 4]) = pk.u4;
            }
            ps += __shfl_xor(ps, 16);
            ps += __shfl_xor(ps, 32);
            l_i = l_i * alpha + ps;
            if (quad == 0) aL[w * 16 + l15] = alpha;
        }
        __syncthreads();  // barrier 2: drains gll (V ready) + P/alpha visible
        // rescale
        float av[4];
#pragma unroll
        for (int it = 0; it < 4; it++) av[it] = aL[it * 16 + l15];
#pragma unroll
        for (int ct = 0; ct < 4; ct++)
#pragma unroll
            for (int it = 0; it < 4; it++) acc[ct][it] *= av[it];
        // PV: A = V (m=c), B = P (n=i); each vf feeds 4 MFMAs
#pragma unroll
        for (int ks = 0; ks < 2; ks++) {
            bf16x8 vf[4];
#pragma unroll
            for (int ct = 0; ct < 4; ct++) {
                int cr = w * 64 + ct * 16 + l15;
                vf[ct] = ld_bf16x8(&Vt[cr * 64 + ((ks * 32 + quad * 8) ^ swz)]);
            }
#pragma unroll
            for (int it = 0; it < 4; it++) {
                bf16x8 pf = ld_bf16x8(&Pt[(it * 16 + l15) * 72 + ks * 32 + quad * 8]);
#pragma unroll
                for (int ct = 0; ct < 4; ct++)
                    acc[ct][it] = __builtin_amdgcn_mfma_f32_16x16x32_bf16(vf[ct], pf, acc[ct][it], 0, 0, 0);
            }
        }
    }
    // epilogue: out = gamma * O / l + x
    __syncthreads();
    if (quad == 0) lL[w * 16 + l15] = l_i;
    __syncthreads();
    float linv[4];
#pragma unroll
    for (int it = 0; it < 4; it++) linv[it] = 1.0f / lL[it * 16 + l15];
    float g = gamma[0];
#pragma unroll
    for (int ct = 0; ct < 4; ct++) {
#pragma unroll
        for (int it = 0; it < 4; it++) {
#pragma unroll
            for (int r = 0; r < 4; r++) {
                int c = w * 64 + ct * 16 + quad * 4 + r;
                int i = i0 + it * 16 + l15;
                size_t off = ((size_t)b * CC + c) * NND + i;
                out[off] = g * (acc[ct][it][r] * linv[it]) + x[off];
            }
        }
    }
}

extern "C" void kernel_launch(void* const* d_in, const int* in_sizes, int n_in,
                              void* d_out, int out_size, void* d_ws, size_t ws_size,
                              hipStream_t stream) {
    const float* x = (const float*)d_in[0];
    const float* wq = (const float*)d_in[1];
    const float* bq = (const float*)d_in[2];
    const float* wk = (const float*)d_in[3];
    const float* bk = (const float*)d_in[4];
    const float* wv = (const float*)d_in[5];
    const float* bv = (const float*)d_in[6];
    const float* gamma = (const float*)d_in[7];
    float* out = (float*)d_out;

    char* ws = (char*)d_ws;
    __bf16* qb = (__bf16*)ws;                       // 8*4096*32*2  = 2097152
    __bf16* kb = (__bf16*)(ws + 2097152);           // 2097152
    __bf16* vb = (__bf16*)(ws + 2 * 2097152);       // 8*256*4096*2 = 16777216
    __bf16* wqkb = (__bf16*)(ws + 2 * 2097152 + 16777216);           // 32768
    __bf16* wvb = (__bf16*)(ws + 2 * 2097152 + 16777216 + 32768);    // 131072

    prep_weights<<<320, 256, 0, stream>>>(wq, wk, wv, wqkb, wvb);
    proj_qkv<<<512, 256, 0, stream>>>(x, wqkb, wvb, bq, bk, bv, qb, kb, vb);
    attention<<<512, 256, 0, stream>>>(qb, kb, vb, gamma, x, out);
}